// Round 12
// baseline (202.735 us; speedup 1.0000x reference)
//
#include <hip/hip_runtime.h>

#define EMBED 1024
#define C3    3072
#define NHEAD 16
#define HDIM  64
#define BB    4
#define TT    2048
#define MTOK  8192   // BB*TT

typedef __bf16 bf16;
typedef __bf16 bf16x4 __attribute__((ext_vector_type(4)));
typedef __bf16 bf16x8 __attribute__((ext_vector_type(8)));
typedef float  f32x4  __attribute__((ext_vector_type(4)));
typedef float  f32x16 __attribute__((ext_vector_type(16)));
typedef unsigned int u32;

__device__ __forceinline__ void gload_lds16(const bf16* g, bf16* l) {
  __builtin_amdgcn_global_load_lds((__attribute__((address_space(1))) void*)g,
                                   (__attribute__((address_space(3))) void*)l,
                                   16, 0, 0);
}

__device__ __forceinline__ u32 pkbf(float lo, float hi_) {
  union { bf16 h[2]; u32 w; } u;
  u.h[0] = (bf16)lo; u.h[1] = (bf16)hi_;
  return u.w;
}

union upw { u32 w[4]; bf16x8 v; };

// ---------------- fused fp32 -> bf16 convert ----------------
__global__ __launch_bounds__(256) void cvt_all(const float* __restrict__ x,
                                               const float* __restrict__ w1,
                                               const float* __restrict__ w2,
                                               bf16* __restrict__ xb,
                                               bf16* __restrict__ wqkv,
                                               bf16* __restrict__ wproj) {
  const int N1 = MTOK * EMBED, N2 = C3 * EMBED, N3 = EMBED * EMBED;
  int i = (blockIdx.x * blockDim.x + threadIdx.x) * 4;
  const float* src; bf16* dst;
  if (i < N1)           { src = x + i;            dst = xb + i; }
  else if (i < N1 + N2) { src = w1 + (i - N1);    dst = wqkv + (i - N1); }
  else if (i < N1 + N2 + N3) { src = w2 + (i - N1 - N2); dst = wproj + (i - N1 - N2); }
  else return;
  float4 v = *reinterpret_cast<const float4*>(src);
  bf16x4 o;
  o[0] = (bf16)v.x; o[1] = (bf16)v.y; o[2] = (bf16)v.z; o[3] = (bf16)v.w;
  *reinterpret_cast<bf16x4*>(dst) = o;
}

// ================= GEMM core (BK=64, swizzled LDS, hoisted addressing) =============
__device__ __forceinline__ void gemm_core(const bf16* __restrict__ A,
                                          const bf16* __restrict__ W,
                                          int K, int bm0, int bn0,
                                          int wm, int wn, int l15, int lg,
                                          f32x4 (&acc)[4][4]) {
  __shared__ __align__(16) bf16 lA[128 * 64];
  __shared__ __align__(16) bf16 lB[128 * 64];
  const int tid  = threadIdx.x;
  const int grow = tid >> 3;
  const int gseg = tid & 7;

  const bf16* srcA[4];
  const bf16* srcB[4];
#pragma unroll
  for (int r = 0; r < 4; ++r) {
    const int row = r * 32 + grow;
    const int seg = gseg ^ (row & 7);
    srcA[r] = A + (size_t)(bm0 + row) * K + seg * 8;
    srcB[r] = W + (size_t)(bn0 + row) * K + seg * 8;
  }
  int offA[2][4], offB[2][4];
#pragma unroll
  for (int kk = 0; kk < 2; ++kk) {
#pragma unroll
    for (int i = 0; i < 4; ++i) {
      const int rowA = wm + i * 16 + l15;
      const int rowB = wn + i * 16 + l15;
      offA[kk][i] = rowA * 128 + ((kk * 64 + lg * 16) ^ ((rowA & 7) << 4));
      offB[kk][i] = rowB * 128 + ((kk * 64 + lg * 16) ^ ((rowB & 7) << 4));
    }
  }

  for (int kt = 0; kt < K; kt += 64) {
#pragma unroll
    for (int r = 0; r < 4; ++r) {
      gload_lds16(srcA[r] + kt, &lA[(r * 256 + tid) * 8]);
      gload_lds16(srcB[r] + kt, &lB[(r * 256 + tid) * 8]);
    }
    __syncthreads();
    const char* Ab = (const char*)lA;
    const char* Bb = (const char*)lB;
#pragma unroll
    for (int kk = 0; kk < 2; ++kk) {
      bf16x8 af[4], bf_[4];
#pragma unroll
      for (int i = 0; i < 4; ++i) af[i]  = *reinterpret_cast<const bf16x8*>(Ab + offA[kk][i]);
#pragma unroll
      for (int j = 0; j < 4; ++j) bf_[j] = *reinterpret_cast<const bf16x8*>(Bb + offB[kk][j]);
#pragma unroll
      for (int i = 0; i < 4; ++i)
#pragma unroll
        for (int j = 0; j < 4; ++j)
          acc[i][j] = __builtin_amdgcn_mfma_f32_16x16x32_bf16(af[i], bf_[j],
                                                              acc[i][j], 0, 0, 0);
    }
    __syncthreads();
  }
}

// ---------------- GEMM1 ----------------
__global__ __launch_bounds__(256) void gemm_qkv(const bf16* __restrict__ A,
                                                const bf16* __restrict__ W,
                                                const float* __restrict__ bias,
                                                bf16* __restrict__ Qh,
                                                bf16* __restrict__ Kh,
                                                bf16* __restrict__ VhT) {
  const int tid  = threadIdx.x;
  const int lane = tid & 63, wave = tid >> 6;
  const int wm   = (wave >> 1) * 64;
  const int wn   = (wave & 1) * 64;
  const int bn0  = blockIdx.x * 128;
  const int bm0  = blockIdx.y * 128;
  const int l15  = lane & 15, lg = lane >> 4;

  f32x4 acc[4][4] = {};
  gemm_core(A, W, EMBED, bm0, bn0, wm, wn, l15, lg, acc);

  const int sec = bn0 >> 10;
#pragma unroll
  for (int i = 0; i < 4; ++i)
#pragma unroll
    for (int j = 0; j < 4; ++j) {
      const int col = bn0 + wn + j * 16 + l15;
      const float bs = bias[col];
      const int c2 = col & 1023, hh = c2 >> 6, dd = c2 & 63;
      const int rowb = bm0 + wm + i * 16 + lg * 4;
      const int bb = rowb >> 11, t0 = rowb & 2047;
      const int bh = bb * 16 + hh;
      if (sec < 2) {
        bf16* dst = (sec ? Kh : Qh) + ((size_t)bh * TT + t0) * HDIM + dd;
#pragma unroll
        for (int r = 0; r < 4; ++r) dst[(size_t)r * HDIM] = (bf16)(acc[i][j][r] + bs);
      } else {
        bf16x4 o4;
#pragma unroll
        for (int r = 0; r < 4; ++r) o4[r] = (bf16)(acc[i][j][r] + bs);
        *reinterpret_cast<bf16x4*>(VhT + ((size_t)bh * HDIM + dd) * TT + t0) = o4;
      }
    }
}

// ---------------- GEMM2 ----------------
__global__ __launch_bounds__(256) void gemm_bt(const bf16* __restrict__ A,
                                               const bf16* __restrict__ W,
                                               const float* __restrict__ bias,
                                               float* __restrict__ Cf,
                                               int M, int N, int K) {
  const int tid  = threadIdx.x;
  const int lane = tid & 63, wave = tid >> 6;
  const int wm   = (wave >> 1) * 64;
  const int wn   = (wave & 1) * 64;
  const int bn0  = blockIdx.x * 128;
  const int bm0  = blockIdx.y * 128;
  const int l15  = lane & 15, lg = lane >> 4;

  f32x4 acc[4][4] = {};
  gemm_core(A, W, K, bm0, bn0, wm, wn, l15, lg, acc);

#pragma unroll
  for (int i = 0; i < 4; ++i)
#pragma unroll
    for (int j = 0; j < 4; ++j) {
      int col = bn0 + wn + j * 16 + l15;
      float bs = bias[col];
#pragma unroll
      for (int r = 0; r < 4; ++r) {
        int row = bm0 + wm + i * 16 + lg * 4 + r;
        Cf[(size_t)row * N + col] = acc[i][j][r] + bs;
      }
    }
}

// ================= attention building blocks =================
__device__ __forceinline__ void load_kf(const char* kbase, bf16x8 (&kf0)[4], bf16x8 (&kf1)[4],
                                        int l31, int hi, int swz) {
#pragma unroll
  for (int dc = 0; dc < 4; ++dc) {
    kf0[dc] = *reinterpret_cast<const bf16x8*>(kbase + l31 * 128 + (((2 * dc + hi) * 16) ^ swz));
    kf1[dc] = *reinterpret_cast<const bf16x8*>(kbase + (32 + l31) * 128 + (((2 * dc + hi) * 16) ^ swz));
  }
}

__device__ __forceinline__ void qk_one(const bf16x8 (&kf0)[4], const bf16x8 (&kf1)[4],
                                       const bf16x8 (&qfr)[4], f32x16& s0, f32x16& s1) {
  f32x16 a = {}, b = {};
  __builtin_amdgcn_s_setprio(1);
#pragma unroll
  for (int dc = 0; dc < 4; ++dc) {
    a = __builtin_amdgcn_mfma_f32_32x32x16_bf16(kf0[dc], qfr[dc], a, 0, 0, 0);
    b = __builtin_amdgcn_mfma_f32_32x32x16_bf16(kf1[dc], qfr[dc], b, 0, 0, 0);
  }
  __builtin_amdgcn_s_setprio(0);
  s0 = a; s1 = b;
}

// softmax + pack + PV for one band's 32q x 64kv scores (R10-verified math)
__device__ __forceinline__ void fin_band(const char* vbase, f32x16& s0, f32x16& s1,
                                         f32x16 (&oacc)[2], float& mrun, float& srun,
                                         const int kv0, const int q0w,
                                         const int l31, const int hi, const int swz) {
  if (kv0 + 63 > q0w) {
    const int qg = q0w + l31;
#pragma unroll
    for (int r = 0; r < 16; ++r) {
      const int kvb = kv0 + (r & 3) + 8 * (r >> 2) + 4 * hi;
      if (kvb > qg)      s0[r] = -3e38f;
      if (kvb + 32 > qg) s1[r] = -3e38f;
    }
  }
  float m8[8];
#pragma unroll
  for (int i = 0; i < 8; ++i)
    m8[i] = fmaxf(fmaxf(s0[i], s0[i + 8]), fmaxf(s1[i], s1[i + 8]));
#pragma unroll
  for (int st = 4; st > 0; st >>= 1)
#pragma unroll
    for (int i = 0; i < st; ++i) m8[i] = fmaxf(m8[i], m8[i + st]);
  float mx = fmaxf(m8[0], __shfl_xor(m8[0], 32));

  float mref = mrun;
  if (!__all(mx <= mrun + 8.0f)) {
    const float mnew = fmaxf(mrun, mx);
    const float corr = __builtin_amdgcn_exp2f(mrun - mnew);
    mrun = mnew; mref = mnew;
    srun *= corr;
#pragma unroll
    for (int r = 0; r < 16; ++r) { oacc[0][r] *= corr; oacc[1][r] *= corr; }
  }

  float psum = 0.0f;
#pragma unroll
  for (int r = 0; r < 16; ++r) {
    s0[r] = __builtin_amdgcn_exp2f(s0[r] - mref);
    s1[r] = __builtin_amdgcn_exp2f(s1[r] - mref);
    psum += s0[r] + s1[r];
  }
  srun += psum;

  upw pw[4];
#pragma unroll
  for (int cl = 0; cl < 2; ++cl) {
    {
      u32 a01 = pkbf(s0[8 * cl + 0], s0[8 * cl + 1]);
      u32 a23 = pkbf(s0[8 * cl + 2], s0[8 * cl + 3]);
      u32 b01 = pkbf(s0[8 * cl + 4], s0[8 * cl + 5]);
      u32 b23 = pkbf(s0[8 * cl + 6], s0[8 * cl + 7]);
      asm("v_permlane32_swap_b32 %0, %1" : "+v"(a01), "+v"(b01));
      asm("v_permlane32_swap_b32 %0, %1" : "+v"(a23), "+v"(b23));
      pw[cl].w[0] = a01; pw[cl].w[1] = a23; pw[cl].w[2] = b01; pw[cl].w[3] = b23;
    }
    {
      u32 a01 = pkbf(s1[8 * cl + 0], s1[8 * cl + 1]);
      u32 a23 = pkbf(s1[8 * cl + 2], s1[8 * cl + 3]);
      u32 b01 = pkbf(s1[8 * cl + 4], s1[8 * cl + 5]);
      u32 b23 = pkbf(s1[8 * cl + 6], s1[8 * cl + 7]);
      asm("v_permlane32_swap_b32 %0, %1" : "+v"(a01), "+v"(b01));
      asm("v_permlane32_swap_b32 %0, %1" : "+v"(a23), "+v"(b23));
      pw[2 + cl].w[0] = a01; pw[2 + cl].w[1] = a23; pw[2 + cl].w[2] = b01; pw[2 + cl].w[3] = b23;
    }
  }

  __builtin_amdgcn_s_setprio(1);
#pragma unroll
  for (int dh = 0; dh < 2; ++dh) {
    const char* vrow = vbase + (32 * dh + l31) * 128;
#pragma unroll
    for (int c = 0; c < 4; ++c) {
      bf16x8 vf = *reinterpret_cast<const bf16x8*>(vrow + (((2 * c + hi) * 16) ^ swz));
      oacc[dh] = __builtin_amdgcn_mfma_f32_32x32x16_bf16(vf, pw[c].v, oacc[dh], 0, 0, 0);
    }
  }
  __builtin_amdgcn_s_setprio(0);
}

__device__ __forceinline__ void stage_tile(const bf16* kS0, const bf16* kS1,
                                           const bf16* vS0, const bf16* vS1,
                                           int kv, bf16* kb, bf16* vb, int tid) {
  gload_lds16(kS0 + (size_t)kv * HDIM, kb + tid * 8);
  gload_lds16(kS1 + (size_t)kv * HDIM, kb + (tid + 256) * 8);
  gload_lds16(vS0 + kv, vb + tid * 8);
  gload_lds16(vS1 + kv, vb + (tid + 256) * 8);
}

// ---------------- causal flash attention: paired bands, 2-deep software pipeline ----
// Per half-iter t: stage(t+1) || finish(t-1) [softmax VALU + PV] || QK(t) [MFMA].
// 4 LDS buffers; one barrier per tile; H band branchless (masked tiles add 0).
__global__ __launch_bounds__(256, 2) void attn_kernel(const bf16* __restrict__ Qh,
                                                      const bf16* __restrict__ Kh,
                                                      const bf16* __restrict__ VhT,
                                                      bf16* __restrict__ aout) {
  __shared__ __align__(16) bf16 lK[4][64 * 64];
  __shared__ __align__(16) bf16 lVT[4][64 * 64];
  const int tid  = threadIdx.x;
  const int lane = tid & 63, wave = tid >> 6;
  const int l31  = lane & 31;
  const int hi   = lane >> 5;
  const int bid  = blockIdx.x;              // 0..511
  const int bh   = bid & 63;
  const int p    = bid >> 6;                // 0..7
  const int qtH  = 15 - p, qtL = p;
  const int b    = bh >> 4, h = bh & 15;
  const int q0H  = qtH * 128 + wave * 32;
  const int q0L  = qtL * 128 + wave * 32;
  const size_t tb = (size_t)b * TT;
  const int swz  = (l31 & 7) << 4;

  const float QSCALE = 0.18033688011112042f;
  bf16x8 qfrH[4], qfrL[4];
  {
    const bf16* qrowH = Qh + ((size_t)bh * TT + q0H + l31) * HDIM;
    const bf16* qrowL = Qh + ((size_t)bh * TT + q0L + l31) * HDIM;
#pragma unroll
    for (int dc = 0; dc < 4; ++dc) {
      bf16x8 vH = *reinterpret_cast<const bf16x8*>(qrowH + dc * 16 + hi * 8);
      bf16x8 vL = *reinterpret_cast<const bf16x8*>(qrowL + dc * 16 + hi * 8);
      bf16x8 oH, oL;
#pragma unroll
      for (int j = 0; j < 8; ++j) {
        oH[j] = (bf16)((float)vH[j] * QSCALE);
        oL[j] = (bf16)((float)vL[j] * QSCALE);
      }
      qfrH[dc] = oH; qfrL[dc] = oL;
    }
  }

  f32x16 oaccH[2] = {}, oaccL[2] = {};
  float mH = -3e38f, sHr = 0.0f, mL = -3e38f, sLr = 0.0f;

  const int r0 = tid >> 3, sg = tid & 7;
  const bf16* kS0 = Kh + ((size_t)bh * TT + r0) * HDIM + (size_t)(sg ^ (r0 & 7)) * 8;
  const bf16* kS1 = Kh + ((size_t)bh * TT + 32 + r0) * HDIM + (size_t)(sg ^ (r0 & 7)) * 8;
  const bf16* vS0 = VhT + ((size_t)bh * HDIM + r0) * TT + (size_t)(sg ^ (r0 & 7)) * 8;
  const bf16* vS1 = VhT + ((size_t)bh * HDIM + 32 + r0) * TT + (size_t)(sg ^ (r0 & 7)) * 8;

  const int nkv = 2 * qtH + 2;   // always even, >= 18

  // A/B pipeline states (tile parity: even -> A, odd -> B)
  f32x16 sAh0, sAh1, sAl0, sAl1;
  f32x16 sBh0, sBh1, sBl0, sBl1;

#define HALF_ITER(T, NH0, NH1, NL0, NL1, OH0, OH1, OL0, OL1)                              \
  do {                                                                                    \
    const int t_ = (T);                                                                   \
    if (t_ + 1 < nkv)                                                                     \
      stage_tile(kS0, kS1, vS0, vS1, (t_ + 1) * 64,                                       \
                 &lK[(t_ + 1) & 3][0], &lVT[(t_ + 1) & 3][0], tid);                       \
    {                                                                                     \
      const char* vb_ = (const char*)&lVT[(t_ - 1) & 3][0];                               \
      const int pk_ = (t_ - 1) * 64;                                                      \
      fin_band(vb_, OH0, OH1, oaccH, mH, sHr, pk_, q0H, l31, hi, swz);                    \
      if (pk_ <= q0L + 31)                                                                \
        fin_band(vb_, OL0, OL1, oaccL, mL, sLr, pk_, q0L, l31, hi, swz);                  \
    }                                                                                     \
    {                                                                                     \
      const char* kb_ = (const char*)&lK[t_ & 3][0];                                      \
      bf16x8 kf0_[4], kf1_[4];                                                            \
      load_kf(kb_, kf0_, kf1_, l31, hi, swz);                                             \
      qk_one(kf0_, kf1_, qfrH, NH0, NH1);                                                 \
      if (t_ * 64 <= q0L + 31) qk_one(kf0_, kf1_, qfrL, NL0, NL1);                        \
    }                                                                                     \
    __syncthreads();                                                                      \
  } while (0)

  // prologue: tile 0
  stage_tile(kS0, kS1, vS0, vS1, 0, &lK[0][0], &lVT[0][0], tid);
  __syncthreads();
  {
    stage_tile(kS0, kS1, vS0, vS1, 64, &lK[1][0], &lVT[1][0], tid);
    bf16x8 kf0_[4], kf1_[4];
    load_kf((const char*)&lK[0][0], kf0_, kf1_, l31, hi, swz);
    qk_one(kf0_, kf1_, qfrH, sAh0, sAh1);
    qk_one(kf0_, kf1_, qfrL, sAl0, sAl1);   // L always active at t=0
    __syncthreads();
  }

  int t = 1;
  for (; t + 1 < nkv; t += 2) {
    HALF_ITER(t,     sBh0, sBh1, sBl0, sBl1, sAh0, sAh1, sAl0, sAl1);
    HALF_ITER(t + 1, sAh0, sAh1, sAl0, sAl1, sBh0, sBh1, sBl0, sBl1);
  }
  // t == nkv-1 (odd): QK into B, finish A(nkv-2)
  HALF_ITER(t, sBh0, sBh1, sBl0, sBl1, sAh0, sAh1, sAl0, sAl1);
  // final finish: tile nkv-1 (state B)
  {
    const char* vb_ = (const char*)&lVT[(nkv - 1) & 3][0];
    const int pk_ = (nkv - 1) * 64;
    fin_band(vb_, sBh0, sBh1, oaccH, mH, sHr, pk_, q0H, l31, hi, swz);
    if (pk_ <= q0L + 31)
      fin_band(vb_, sBl0, sBl1, oaccL, mL, sLr, pk_, q0L, l31, hi, swz);
  }
#undef HALF_ITER

  // ---- epilogue: cross-lane rowsum, divide, store (both bands)
#pragma unroll
  for (int band = 0; band < 2; ++band) {
    const f32x16* oacc = band ? oaccL : oaccH;
    float sr = band ? sLr : sHr;
    sr += __shfl_xor(sr, 32);
    const float inv = 1.0f / sr;
    const int q = (band ? q0L : q0H) + l31;
    bf16* orow = aout + (tb + q) * (size_t)EMBED + h * HDIM;
#pragma unroll
    for (int dh = 0; dh < 2; ++dh)
#pragma unroll
      for (int rb = 0; rb < 4; ++rb) {
        bf16x4 o4;
#pragma unroll
        for (int k = 0; k < 4; ++k) o4[k] = (bf16)(oacc[dh][4 * rb + k] * inv);
        *reinterpret_cast<bf16x4*>(orow + 32 * dh + 8 * rb + 4 * hi) = o4;
      }
  }
}

extern "C" void kernel_launch(void* const* d_in, const int* in_sizes, int n_in,
                              void* d_out, int out_size, void* d_ws, size_t ws_size,
                              hipStream_t stream) {
  const float* x      = (const float*)d_in[0];
  const float* qkv_w  = (const float*)d_in[1];
  const float* qkv_b  = (const float*)d_in[2];
  const float* proj_w = (const float*)d_in[3];
  const float* proj_b = (const float*)d_in[4];
  float* out = (float*)d_out;

  const size_t QSZ = (size_t)BB * NHEAD * TT * HDIM;
  char* ws = (char*)d_ws;
  bf16* xb    = (bf16*)ws;
  bf16* wqkv  = xb + (size_t)MTOK * EMBED;
  bf16* wproj = wqkv + (size_t)C3 * EMBED;
  bf16* Qh    = wproj + (size_t)EMBED * EMBED;
  bf16* Kh    = Qh + QSZ;
  bf16* VhT   = Kh + QSZ;
  bf16* aob   = xb;   // alias: xb dead after gemm_qkv

  const int NCVT = (MTOK * EMBED + C3 * EMBED + EMBED * EMBED) / 4;
  cvt_all<<<dim3((NCVT + 255) / 256), dim3(256), 0, stream>>>(x, qkv_w, proj_w,
                                                              xb, wqkv, wproj);

  gemm_qkv<<<dim3(C3 / 128, MTOK / 128), dim3(256), 0, stream>>>(xb, wqkv, qkv_b, Qh, Kh, VhT);

  attn_kernel<<<dim3(512), dim3(256), 0, stream>>>(Qh, Kh, VhT, aob);

  gemm_bt<<<dim3(EMBED / 128, MTOK / 128), dim3(256), 0, stream>>>(
      aob, wproj, proj_b, out, MTOK, EMBED, EMBED);
}

// Round 13
// 181.132 us; speedup vs baseline: 1.1193x; 1.1193x over previous
//
#include <hip/hip_runtime.h>

#define EMBED 1024
#define C3    3072
#define NHEAD 16
#define HDIM  64
#define BB    4
#define TT    2048
#define MTOK  8192   // BB*TT

typedef __bf16 bf16;
typedef __bf16 bf16x4 __attribute__((ext_vector_type(4)));
typedef __bf16 bf16x8 __attribute__((ext_vector_type(8)));
typedef float  f32x4  __attribute__((ext_vector_type(4)));
typedef float  f32x16 __attribute__((ext_vector_type(16)));
typedef unsigned int u32;

__device__ __forceinline__ void gload_lds16(const bf16* g, bf16* l) {
  __builtin_amdgcn_global_load_lds((__attribute__((address_space(1))) void*)g,
                                   (__attribute__((address_space(3))) void*)l,
                                   16, 0, 0);
}

__device__ __forceinline__ u32 pkbf(float lo, float hi_) {
  union { bf16 h[2]; u32 w; } u;
  u.h[0] = (bf16)lo; u.h[1] = (bf16)hi_;
  return u.w;
}

union upw { u32 w[4]; bf16x8 v; };

// ---------------- fused fp32 -> bf16 convert ----------------
__global__ __launch_bounds__(256) void cvt_all(const float* __restrict__ x,
                                               const float* __restrict__ w1,
                                               const float* __restrict__ w2,
                                               bf16* __restrict__ xb,
                                               bf16* __restrict__ wqkv,
                                               bf16* __restrict__ wproj) {
  const int N1 = MTOK * EMBED, N2 = C3 * EMBED, N3 = EMBED * EMBED;
  int i = (blockIdx.x * blockDim.x + threadIdx.x) * 4;
  const float* src; bf16* dst;
  if (i < N1)           { src = x + i;            dst = xb + i; }
  else if (i < N1 + N2) { src = w1 + (i - N1);    dst = wqkv + (i - N1); }
  else if (i < N1 + N2 + N3) { src = w2 + (i - N1 - N2); dst = wproj + (i - N1 - N2); }
  else return;
  float4 v = *reinterpret_cast<const float4*>(src);
  bf16x4 o;
  o[0] = (bf16)v.x; o[1] = (bf16)v.y; o[2] = (bf16)v.z; o[3] = (bf16)v.w;
  *reinterpret_cast<bf16x4*>(dst) = o;
}

// ===== GEMM core: 128x128 tile, BK=64, swizzled LDS, counted-vmcnt pipeline =====
// 2 buffers; tile t+1 staged as two half-tiles (4 loads each) at the start of
// tile t's two k-phases. vmcnt(4) once per tile (never 0 in the loop);
// raw s_barrier (no compiler vmcnt(0) drain).
__device__ __forceinline__ void gemm_core(const bf16* __restrict__ A,
                                          const bf16* __restrict__ W,
                                          int K, int bm0, int bn0,
                                          int wm, int wn, int l15, int lg,
                                          f32x4 (&acc)[4][4]) {
  __shared__ __align__(16) bf16 lA[2][128 * 64];
  __shared__ __align__(16) bf16 lB[2][128 * 64];
  const int tid  = threadIdx.x;
  const int grow = tid >> 3;      // 0..31
  const int gseg = tid & 7;

  const bf16* srcA[4];
  const bf16* srcB[4];
#pragma unroll
  for (int r = 0; r < 4; ++r) {
    const int row = r * 32 + grow;
    const int seg = gseg ^ (row & 7);
    srcA[r] = A + (size_t)(bm0 + row) * K + seg * 8;
    srcB[r] = W + (size_t)(bn0 + row) * K + seg * 8;
  }
  int offA[2][4], offB[2][4];
#pragma unroll
  for (int kk = 0; kk < 2; ++kk) {
#pragma unroll
    for (int i = 0; i < 4; ++i) {
      const int rowA = wm + i * 16 + l15;
      const int rowB = wn + i * 16 + l15;
      offA[kk][i] = rowA * 128 + ((kk * 64 + lg * 16) ^ ((rowA & 7) << 4));
      offB[kk][i] = rowB * 128 + ((kk * 64 + lg * 16) ^ ((rowB & 7) << 4));
    }
  }

  const int nt = K >> 6;
  // prologue: stage tile 0 (both halves, 8 loads)
#pragma unroll
  for (int r = 0; r < 4; ++r) {
    gload_lds16(srcA[r], &lA[0][(r * 256 + tid) * 8]);
    gload_lds16(srcB[r], &lB[0][(r * 256 + tid) * 8]);
  }

  for (int t = 0; t < nt; ++t) {
    const int cur = t & 1;
    const int kt1 = (t + 1) << 6;
    const bool pf = (t + 1 < nt);

    // ---- phase 0: issue half-0 of t+1, counted wait for tile t, barrier, k0 MFMA
    if (pf) {
#pragma unroll
      for (int r = 0; r < 2; ++r) {
        gload_lds16(srcA[r] + kt1, &lA[cur ^ 1][(r * 256 + tid) * 8]);
        gload_lds16(srcB[r] + kt1, &lB[cur ^ 1][(r * 256 + tid) * 8]);
      }
      asm volatile("s_waitcnt vmcnt(4)" ::: "memory");
    } else {
      asm volatile("s_waitcnt vmcnt(0)" ::: "memory");
    }
    __builtin_amdgcn_sched_barrier(0);
    __builtin_amdgcn_s_barrier();
    __builtin_amdgcn_sched_barrier(0);

    const char* Ab = (const char*)&lA[cur][0];
    const char* Bb = (const char*)&lB[cur][0];
#pragma unroll
    for (int kk = 0; kk < 2; ++kk) {
      if (kk == 1 && pf) {   // ---- phase 1: issue half-1 of t+1
#pragma unroll
        for (int r = 2; r < 4; ++r) {
          gload_lds16(srcA[r] + kt1, &lA[cur ^ 1][(r * 256 + tid) * 8]);
          gload_lds16(srcB[r] + kt1, &lB[cur ^ 1][(r * 256 + tid) * 8]);
        }
      }
      bf16x8 af[4], bf_[4];
#pragma unroll
      for (int i = 0; i < 4; ++i) af[i]  = *reinterpret_cast<const bf16x8*>(Ab + offA[kk][i]);
#pragma unroll
      for (int j = 0; j < 4; ++j) bf_[j] = *reinterpret_cast<const bf16x8*>(Bb + offB[kk][j]);
      __builtin_amdgcn_s_setprio(1);
#pragma unroll
      for (int i = 0; i < 4; ++i)
#pragma unroll
        for (int j = 0; j < 4; ++j)
          acc[i][j] = __builtin_amdgcn_mfma_f32_16x16x32_bf16(af[i], bf_[j],
                                                              acc[i][j], 0, 0, 0);
      __builtin_amdgcn_s_setprio(0);
    }
    __builtin_amdgcn_s_barrier();       // all reads of buf[cur] done before t+1
    __builtin_amdgcn_sched_barrier(0);  // re-stages it at its phase 0
  }
}

// ---------------- GEMM1: qkv = x @ qkv_w^T + b, split into per-head layouts --------
__global__ __launch_bounds__(256) void gemm_qkv(const bf16* __restrict__ A,
                                                const bf16* __restrict__ W,
                                                const float* __restrict__ bias,
                                                bf16* __restrict__ Qh,
                                                bf16* __restrict__ Kh,
                                                bf16* __restrict__ VhT) {
  const int tid  = threadIdx.x;
  const int lane = tid & 63, wave = tid >> 6;
  const int wm   = (wave >> 1) * 64;
  const int wn   = (wave & 1) * 64;
  const int bn0  = blockIdx.x * 128;
  const int bm0  = blockIdx.y * 128;
  const int l15  = lane & 15, lg = lane >> 4;

  f32x4 acc[4][4] = {};
  gemm_core(A, W, EMBED, bm0, bn0, wm, wn, l15, lg, acc);

  const int sec = bn0 >> 10;   // 0=Q 1=K 2=V, uniform per block
#pragma unroll
  for (int i = 0; i < 4; ++i)
#pragma unroll
    for (int j = 0; j < 4; ++j) {
      const int col = bn0 + wn + j * 16 + l15;
      const float bs = bias[col];
      const int c2 = col & 1023, hh = c2 >> 6, dd = c2 & 63;
      const int rowb = bm0 + wm + i * 16 + lg * 4;
      const int bb = rowb >> 11, t0 = rowb & 2047;
      const int bh = bb * 16 + hh;
      if (sec < 2) {
        bf16* dst = (sec ? Kh : Qh) + ((size_t)bh * TT + t0) * HDIM + dd;
#pragma unroll
        for (int r = 0; r < 4; ++r) dst[(size_t)r * HDIM] = (bf16)(acc[i][j][r] + bs);
      } else {
        bf16x4 o4;
#pragma unroll
        for (int r = 0; r < 4; ++r) o4[r] = (bf16)(acc[i][j][r] + bs);
        *reinterpret_cast<bf16x4*>(VhT + ((size_t)bh * HDIM + dd) * TT + t0) = o4;
      }
    }
}

// ---------------- GEMM2: out = A @ W^T + b (fp32 out) ----------------
__global__ __launch_bounds__(256) void gemm_bt(const bf16* __restrict__ A,
                                               const bf16* __restrict__ W,
                                               const float* __restrict__ bias,
                                               float* __restrict__ Cf,
                                               int M, int N, int K) {
  const int tid  = threadIdx.x;
  const int lane = tid & 63, wave = tid >> 6;
  const int wm   = (wave >> 1) * 64;
  const int wn   = (wave & 1) * 64;
  const int bn0  = blockIdx.x * 128;
  const int bm0  = blockIdx.y * 128;
  const int l15  = lane & 15, lg = lane >> 4;

  f32x4 acc[4][4] = {};
  gemm_core(A, W, K, bm0, bn0, wm, wn, l15, lg, acc);

#pragma unroll
  for (int i = 0; i < 4; ++i)
#pragma unroll
    for (int j = 0; j < 4; ++j) {
      int col = bn0 + wn + j * 16 + l15;
      float bs = bias[col];
#pragma unroll
      for (int r = 0; r < 4; ++r) {
        int row = bm0 + wm + i * 16 + lg * 4 + r;
        Cf[(size_t)row * N + col] = acc[i][j][r] + bs;
      }
    }
}

// ---------------- one 32q x 64kv attention tile for one band (R10-verified) --------
__device__ __forceinline__ void attn_tile(const char* kbase, const char* vbase,
                                          const bf16x8 (&qfr)[4], f32x16 (&oacc)[2],
                                          float& mrun, float& srun,
                                          const int kv0, const int q0w,
                                          const int l31, const int hi, const int swz) {
  f32x16 s0 = {}, s1 = {};
  __builtin_amdgcn_s_setprio(1);
#pragma unroll
  for (int dc = 0; dc < 4; ++dc) {
    bf16x8 kf = *reinterpret_cast<const bf16x8*>(
        kbase + l31 * 128 + (((2 * dc + hi) * 16) ^ swz));
    s0 = __builtin_amdgcn_mfma_f32_32x32x16_bf16(kf, qfr[dc], s0, 0, 0, 0);
  }
#pragma unroll
  for (int dc = 0; dc < 4; ++dc) {
    bf16x8 kf = *reinterpret_cast<const bf16x8*>(
        kbase + (32 + l31) * 128 + (((2 * dc + hi) * 16) ^ swz));
    s1 = __builtin_amdgcn_mfma_f32_32x32x16_bf16(kf, qfr[dc], s1, 0, 0, 0);
  }
  __builtin_amdgcn_s_setprio(0);

  if (kv0 + 63 > q0w) {
    const int qg = q0w + l31;
#pragma unroll
    for (int r = 0; r < 16; ++r) {
      const int kvb = kv0 + (r & 3) + 8 * (r >> 2) + 4 * hi;
      if (kvb > qg)      s0[r] = -3e38f;
      if (kvb + 32 > qg) s1[r] = -3e38f;
    }
  }

  float m8[8];
#pragma unroll
  for (int i = 0; i < 8; ++i)
    m8[i] = fmaxf(fmaxf(s0[i], s0[i + 8]), fmaxf(s1[i], s1[i + 8]));
#pragma unroll
  for (int st = 4; st > 0; st >>= 1)
#pragma unroll
    for (int i = 0; i < st; ++i) m8[i] = fmaxf(m8[i], m8[i + st]);
  float mx = fmaxf(m8[0], __shfl_xor(m8[0], 32));

  float mref = mrun;
  if (!__all(mx <= mrun + 8.0f)) {
    const float mnew = fmaxf(mrun, mx);
    const float corr = __builtin_amdgcn_exp2f(mrun - mnew);
    mrun = mnew; mref = mnew;
    srun *= corr;
#pragma unroll
    for (int r = 0; r < 16; ++r) { oacc[0][r] *= corr; oacc[1][r] *= corr; }
  }

  float psum = 0.0f;
#pragma unroll
  for (int r = 0; r < 16; ++r) {
    s0[r] = __builtin_amdgcn_exp2f(s0[r] - mref);
    s1[r] = __builtin_amdgcn_exp2f(s1[r] - mref);
    psum += s0[r] + s1[r];
  }
  srun += psum;

  upw pw[4];
#pragma unroll
  for (int cl = 0; cl < 2; ++cl) {
    {
      u32 a01 = pkbf(s0[8 * cl + 0], s0[8 * cl + 1]);
      u32 a23 = pkbf(s0[8 * cl + 2], s0[8 * cl + 3]);
      u32 b01 = pkbf(s0[8 * cl + 4], s0[8 * cl + 5]);
      u32 b23 = pkbf(s0[8 * cl + 6], s0[8 * cl + 7]);
      asm("v_permlane32_swap_b32 %0, %1" : "+v"(a01), "+v"(b01));
      asm("v_permlane32_swap_b32 %0, %1" : "+v"(a23), "+v"(b23));
      pw[cl].w[0] = a01; pw[cl].w[1] = a23; pw[cl].w[2] = b01; pw[cl].w[3] = b23;
    }
    {
      u32 a01 = pkbf(s1[8 * cl + 0], s1[8 * cl + 1]);
      u32 a23 = pkbf(s1[8 * cl + 2], s1[8 * cl + 3]);
      u32 b01 = pkbf(s1[8 * cl + 4], s1[8 * cl + 5]);
      u32 b23 = pkbf(s1[8 * cl + 6], s1[8 * cl + 7]);
      asm("v_permlane32_swap_b32 %0, %1" : "+v"(a01), "+v"(b01));
      asm("v_permlane32_swap_b32 %0, %1" : "+v"(a23), "+v"(b23));
      pw[2 + cl].w[0] = a01; pw[2 + cl].w[1] = a23; pw[2 + cl].w[2] = b01; pw[2 + cl].w[3] = b23;
    }
  }

  __builtin_amdgcn_s_setprio(1);
#pragma unroll
  for (int dh = 0; dh < 2; ++dh) {
    const char* vrow = vbase + (32 * dh + l31) * 128;
#pragma unroll
    for (int c = 0; c < 4; ++c) {
      bf16x8 vf = *reinterpret_cast<const bf16x8*>(vrow + (((2 * c + hi) * 16) ^ swz));
      oacc[dh] = __builtin_amdgcn_mfma_f32_32x32x16_bf16(vf, pw[c].v, oacc[dh], 0, 0, 0);
    }
  }
  __builtin_amdgcn_s_setprio(0);
}

// ---------------- causal flash attention: paired q-bands, shared KV stream (R10) ----
__global__ __launch_bounds__(256, 2) void attn_kernel(const bf16* __restrict__ Qh,
                                                      const bf16* __restrict__ Kh,
                                                      const bf16* __restrict__ VhT,
                                                      bf16* __restrict__ aout) {
  __shared__ __align__(16) bf16 lK[2][64 * 64];
  __shared__ __align__(16) bf16 lVT[2][64 * 64];
  const int tid  = threadIdx.x;
  const int lane = tid & 63, wave = tid >> 6;
  const int l31  = lane & 31;
  const int hi   = lane >> 5;
  const int bid  = blockIdx.x;              // 0..511
  const int bh   = bid & 63;
  const int p    = bid >> 6;                // 0..7
  const int qtH  = 15 - p, qtL = p;
  const int b    = bh >> 4, h = bh & 15;
  const int q0H  = qtH * 128 + wave * 32;
  const int q0L  = qtL * 128 + wave * 32;
  const size_t tb = (size_t)b * TT;
  const int swz  = (l31 & 7) << 4;

  const float QSCALE = 0.18033688011112042f;
  bf16x8 qfrH[4], qfrL[4];
  {
    const bf16* qrowH = Qh + ((size_t)bh * TT + q0H + l31) * HDIM;
    const bf16* qrowL = Qh + ((size_t)bh * TT + q0L + l31) * HDIM;
#pragma unroll
    for (int dc = 0; dc < 4; ++dc) {
      bf16x8 vH = *reinterpret_cast<const bf16x8*>(qrowH + dc * 16 + hi * 8);
      bf16x8 vL = *reinterpret_cast<const bf16x8*>(qrowL + dc * 16 + hi * 8);
      bf16x8 oH, oL;
#pragma unroll
      for (int j = 0; j < 8; ++j) {
        oH[j] = (bf16)((float)vH[j] * QSCALE);
        oL[j] = (bf16)((float)vL[j] * QSCALE);
      }
      qfrH[dc] = oH; qfrL[dc] = oL;
    }
  }

  f32x16 oaccH[2] = {}, oaccL[2] = {};
  float mH = -3e38f, sH = 0.0f, mL = -3e38f, sL = 0.0f;

  const int r0 = tid >> 3, sg = tid & 7;
  const bf16* kS0 = Kh + ((size_t)bh * TT + r0) * HDIM + (size_t)(sg ^ (r0 & 7)) * 8;
  const bf16* kS1 = Kh + ((size_t)bh * TT + 32 + r0) * HDIM + (size_t)(sg ^ (r0 & 7)) * 8;
  const bf16* vS0 = VhT + ((size_t)bh * HDIM + r0) * TT + (size_t)(sg ^ (r0 & 7)) * 8;
  const bf16* vS1 = VhT + ((size_t)bh * HDIM + 32 + r0) * TT + (size_t)(sg ^ (r0 & 7)) * 8;

  const int nkv = 2 * qtH + 2;

  gload_lds16(kS0, &lK[0][tid * 8]);
  gload_lds16(kS1, &lK[0][(tid + 256) * 8]);
  gload_lds16(vS0, &lVT[0][tid * 8]);
  gload_lds16(vS1, &lVT[0][(tid + 256) * 8]);
  __syncthreads();

  int cur = 0;
  for (int t = 0; t < nkv; ++t) {
    const int kv0 = t * 64;
    if (t + 1 < nkv) {
      const int kvn = kv0 + 64;
      gload_lds16(kS0 + (size_t)kvn * HDIM, &lK[cur ^ 1][tid * 8]);
      gload_lds16(kS1 + (size_t)kvn * HDIM, &lK[cur ^ 1][(tid + 256) * 8]);
      gload_lds16(vS0 + kvn, &lVT[cur ^ 1][tid * 8]);
      gload_lds16(vS1 + kvn, &lVT[cur ^ 1][(tid + 256) * 8]);
    }

    const char* kbase = (const char*)&lK[cur][0];
    const char* vbase = (const char*)&lVT[cur][0];
    if (kv0 <= q0H + 31)
      attn_tile(kbase, vbase, qfrH, oaccH, mH, sH, kv0, q0H, l31, hi, swz);
    if (kv0 <= q0L + 31)
      attn_tile(kbase, vbase, qfrL, oaccL, mL, sL, kv0, q0L, l31, hi, swz);

    __syncthreads();   // drains prefetch + protects dbuf swap
    cur ^= 1;
  }

#pragma unroll
  for (int band = 0; band < 2; ++band) {
    const f32x16* oacc = band ? oaccL : oaccH;
    float sr = band ? sL : sH;
    sr += __shfl_xor(sr, 32);
    const float inv = 1.0f / sr;
    const int q = (band ? q0L : q0H) + l31;
    bf16* orow = aout + (tb + q) * (size_t)EMBED + h * HDIM;
#pragma unroll
    for (int dh = 0; dh < 2; ++dh)
#pragma unroll
      for (int rb = 0; rb < 4; ++rb) {
        bf16x4 o4;
#pragma unroll
        for (int k = 0; k < 4; ++k) o4[k] = (bf16)(oacc[dh][4 * rb + k] * inv);
        *reinterpret_cast<bf16x4*>(orow + 32 * dh + 8 * rb + 4 * hi) = o4;
      }
  }
}

extern "C" void kernel_launch(void* const* d_in, const int* in_sizes, int n_in,
                              void* d_out, int out_size, void* d_ws, size_t ws_size,
                              hipStream_t stream) {
  const float* x      = (const float*)d_in[0];
  const float* qkv_w  = (const float*)d_in[1];
  const float* qkv_b  = (const float*)d_in[2];
  const float* proj_w = (const float*)d_in[3];
  const float* proj_b = (const float*)d_in[4];
  float* out = (float*)d_out;

  const size_t QSZ = (size_t)BB * NHEAD * TT * HDIM;
  char* ws = (char*)d_ws;
  bf16* xb    = (bf16*)ws;
  bf16* wqkv  = xb + (size_t)MTOK * EMBED;
  bf16* wproj = wqkv + (size_t)C3 * EMBED;
  bf16* Qh    = wproj + (size_t)EMBED * EMBED;
  bf16* Kh    = Qh + QSZ;
  bf16* VhT   = Kh + QSZ;
  bf16* aob   = xb;   // alias: xb dead after gemm_qkv

  const int NCVT = (MTOK * EMBED + C3 * EMBED + EMBED * EMBED) / 4;
  cvt_all<<<dim3((NCVT + 255) / 256), dim3(256), 0, stream>>>(x, qkv_w, proj_w,
                                                              xb, wqkv, wproj);

  gemm_qkv<<<dim3(C3 / 128, MTOK / 128), dim3(256), 0, stream>>>(xb, wqkv, qkv_b, Qh, Kh, VhT);

  attn_kernel<<<dim3(512), dim3(256), 0, stream>>>(Qh, Kh, VhT, aob);

  gemm_bt<<<dim3(EMBED / 128, MTOK / 128), dim3(256), 0, stream>>>(
      aob, wproj, proj_b, out, MTOK, EMBED, EMBED);
}

// Round 14
// 162.645 us; speedup vs baseline: 1.2465x; 1.1137x over previous
//
#include <hip/hip_runtime.h>

#define EMBED 1024
#define C3    3072
#define NHEAD 16
#define HDIM  64
#define BB    4
#define TT    2048
#define MTOK  8192   // BB*TT

typedef __bf16 bf16;
typedef __bf16 bf16x4 __attribute__((ext_vector_type(4)));
typedef __bf16 bf16x8 __attribute__((ext_vector_type(8)));
typedef float  f32x4  __attribute__((ext_vector_type(4)));
typedef float  f32x16 __attribute__((ext_vector_type(16)));
typedef unsigned int u32;

__device__ __forceinline__ void gload_lds16(const bf16* g, bf16* l) {
  __builtin_amdgcn_global_load_lds((__attribute__((address_space(1))) void*)g,
                                   (__attribute__((address_space(3))) void*)l,
                                   16, 0, 0);
}

__device__ __forceinline__ u32 pkbf(float lo, float hi_) {
  union { bf16 h[2]; u32 w; } u;
  u.h[0] = (bf16)lo; u.h[1] = (bf16)hi_;
  return u.w;
}

union upw { u32 w[4]; bf16x8 v; };

// ---------------- fused fp32 -> bf16 convert ----------------
__global__ __launch_bounds__(256) void cvt_all(const float* __restrict__ x,
                                               const float* __restrict__ w1,
                                               const float* __restrict__ w2,
                                               bf16* __restrict__ xb,
                                               bf16* __restrict__ wqkv,
                                               bf16* __restrict__ wproj) {
  const int N1 = MTOK * EMBED, N2 = C3 * EMBED, N3 = EMBED * EMBED;
  int i = (blockIdx.x * blockDim.x + threadIdx.x) * 4;
  const float* src; bf16* dst;
  if (i < N1)           { src = x + i;            dst = xb + i; }
  else if (i < N1 + N2) { src = w1 + (i - N1);    dst = wqkv + (i - N1); }
  else if (i < N1 + N2 + N3) { src = w2 + (i - N1 - N2); dst = wproj + (i - N1 - N2); }
  else return;
  float4 v = *reinterpret_cast<const float4*>(src);
  bf16x4 o;
  o[0] = (bf16)v.x; o[1] = (bf16)v.y; o[2] = (bf16)v.z; o[3] = (bf16)v.w;
  *reinterpret_cast<bf16x4*>(dst) = o;
}

// ================= GEMM core (R10: BK=64, swizzled LDS, hoisted addressing) ========
__device__ __forceinline__ void gemm_core(const bf16* __restrict__ A,
                                          const bf16* __restrict__ W,
                                          int K, int bm0, int bn0,
                                          int wm, int wn, int l15, int lg,
                                          f32x4 (&acc)[4][4]) {
  __shared__ __align__(16) bf16 lA[128 * 64];
  __shared__ __align__(16) bf16 lB[128 * 64];
  const int tid  = threadIdx.x;
  const int grow = tid >> 3;
  const int gseg = tid & 7;

  const bf16* srcA[4];
  const bf16* srcB[4];
#pragma unroll
  for (int r = 0; r < 4; ++r) {
    const int row = r * 32 + grow;
    const int seg = gseg ^ (row & 7);
    srcA[r] = A + (size_t)(bm0 + row) * K + seg * 8;
    srcB[r] = W + (size_t)(bn0 + row) * K + seg * 8;
  }
  int offA[2][4], offB[2][4];
#pragma unroll
  for (int kk = 0; kk < 2; ++kk) {
#pragma unroll
    for (int i = 0; i < 4; ++i) {
      const int rowA = wm + i * 16 + l15;
      const int rowB = wn + i * 16 + l15;
      offA[kk][i] = rowA * 128 + ((kk * 64 + lg * 16) ^ ((rowA & 7) << 4));
      offB[kk][i] = rowB * 128 + ((kk * 64 + lg * 16) ^ ((rowB & 7) << 4));
    }
  }

  for (int kt = 0; kt < K; kt += 64) {
#pragma unroll
    for (int r = 0; r < 4; ++r) {
      gload_lds16(srcA[r] + kt, &lA[(r * 256 + tid) * 8]);
      gload_lds16(srcB[r] + kt, &lB[(r * 256 + tid) * 8]);
    }
    __syncthreads();
    const char* Ab = (const char*)lA;
    const char* Bb = (const char*)lB;
#pragma unroll
    for (int kk = 0; kk < 2; ++kk) {
      bf16x8 af[4], bf_[4];
#pragma unroll
      for (int i = 0; i < 4; ++i) af[i]  = *reinterpret_cast<const bf16x8*>(Ab + offA[kk][i]);
#pragma unroll
      for (int j = 0; j < 4; ++j) bf_[j] = *reinterpret_cast<const bf16x8*>(Bb + offB[kk][j]);
#pragma unroll
      for (int i = 0; i < 4; ++i)
#pragma unroll
        for (int j = 0; j < 4; ++j)
          acc[i][j] = __builtin_amdgcn_mfma_f32_16x16x32_bf16(af[i], bf_[j],
                                                              acc[i][j], 0, 0, 0);
    }
    __syncthreads();
  }
}

// ---------------- GEMM1: qkv = x @ qkv_w^T + b, split into per-head layouts --------
__global__ __launch_bounds__(256) void gemm_qkv(const bf16* __restrict__ A,
                                                const bf16* __restrict__ W,
                                                const float* __restrict__ bias,
                                                bf16* __restrict__ Qh,
                                                bf16* __restrict__ Kh,
                                                bf16* __restrict__ VhT) {
  const int tid  = threadIdx.x;
  const int lane = tid & 63, wave = tid >> 6;
  const int wm   = (wave >> 1) * 64;
  const int wn   = (wave & 1) * 64;
  const int bn0  = blockIdx.x * 128;
  const int bm0  = blockIdx.y * 128;
  const int l15  = lane & 15, lg = lane >> 4;

  f32x4 acc[4][4] = {};
  gemm_core(A, W, EMBED, bm0, bn0, wm, wn, l15, lg, acc);

  const int sec = bn0 >> 10;   // 0=Q 1=K 2=V, uniform per block
#pragma unroll
  for (int i = 0; i < 4; ++i)
#pragma unroll
    for (int j = 0; j < 4; ++j) {
      const int col = bn0 + wn + j * 16 + l15;
      const float bs = bias[col];
      const int c2 = col & 1023, hh = c2 >> 6, dd = c2 & 63;
      const int rowb = bm0 + wm + i * 16 + lg * 4;
      const int bb = rowb >> 11, t0 = rowb & 2047;
      const int bh = bb * 16 + hh;
      if (sec < 2) {
        bf16* dst = (sec ? Kh : Qh) + ((size_t)bh * TT + t0) * HDIM + dd;
#pragma unroll
        for (int r = 0; r < 4; ++r) dst[(size_t)r * HDIM] = (bf16)(acc[i][j][r] + bs);
      } else {
        bf16x4 o4;
#pragma unroll
        for (int r = 0; r < 4; ++r) o4[r] = (bf16)(acc[i][j][r] + bs);
        *reinterpret_cast<bf16x4*>(VhT + ((size_t)bh * HDIM + dd) * TT + t0) = o4;
      }
    }
}

// ---------------- GEMM2: out = A @ W^T + b (fp32 out) ----------------
__global__ __launch_bounds__(256) void gemm_bt(const bf16* __restrict__ A,
                                               const bf16* __restrict__ W,
                                               const float* __restrict__ bias,
                                               float* __restrict__ Cf,
                                               int M, int N, int K) {
  const int tid  = threadIdx.x;
  const int lane = tid & 63, wave = tid >> 6;
  const int wm   = (wave >> 1) * 64;
  const int wn   = (wave & 1) * 64;
  const int bn0  = blockIdx.x * 128;
  const int bm0  = blockIdx.y * 128;
  const int l15  = lane & 15, lg = lane >> 4;

  f32x4 acc[4][4] = {};
  gemm_core(A, W, K, bm0, bn0, wm, wn, l15, lg, acc);

#pragma unroll
  for (int i = 0; i < 4; ++i)
#pragma unroll
    for (int j = 0; j < 4; ++j) {
      int col = bn0 + wn + j * 16 + l15;
      float bs = bias[col];
#pragma unroll
      for (int r = 0; r < 4; ++r) {
        int row = bm0 + wm + i * 16 + lg * 4 + r;
        Cf[(size_t)row * N + col] = acc[i][j][r] + bs;
      }
    }
}

// ---------------- one 32q x 64kv attention tile (R10-verified math) ----------------
__device__ __forceinline__ void attn_tile(const char* kbase, const char* vbase,
                                          const bf16x8 (&qfr)[4], f32x16 (&oacc)[2],
                                          float& mrun, float& srun,
                                          const int kv0, const int q0w,
                                          const int l31, const int hi, const int swz) {
  f32x16 s0 = {}, s1 = {};
  __builtin_amdgcn_s_setprio(1);
#pragma unroll
  for (int dc = 0; dc < 4; ++dc) {
    bf16x8 kf = *reinterpret_cast<const bf16x8*>(
        kbase + l31 * 128 + (((2 * dc + hi) * 16) ^ swz));
    s0 = __builtin_amdgcn_mfma_f32_32x32x16_bf16(kf, qfr[dc], s0, 0, 0, 0);
  }
#pragma unroll
  for (int dc = 0; dc < 4; ++dc) {
    bf16x8 kf = *reinterpret_cast<const bf16x8*>(
        kbase + (32 + l31) * 128 + (((2 * dc + hi) * 16) ^ swz));
    s1 = __builtin_amdgcn_mfma_f32_32x32x16_bf16(kf, qfr[dc], s1, 0, 0, 0);
  }
  __builtin_amdgcn_s_setprio(0);

  if (kv0 + 63 > q0w) {
    const int qg = q0w + l31;
#pragma unroll
    for (int r = 0; r < 16; ++r) {
      const int kvb = kv0 + (r & 3) + 8 * (r >> 2) + 4 * hi;
      if (kvb > qg)      s0[r] = -3e38f;
      if (kvb + 32 > qg) s1[r] = -3e38f;
    }
  }

  float m8[8];
#pragma unroll
  for (int i = 0; i < 8; ++i)
    m8[i] = fmaxf(fmaxf(s0[i], s0[i + 8]), fmaxf(s1[i], s1[i + 8]));
#pragma unroll
  for (int st = 4; st > 0; st >>= 1)
#pragma unroll
    for (int i = 0; i < st; ++i) m8[i] = fmaxf(m8[i], m8[i + st]);
  float mx = fmaxf(m8[0], __shfl_xor(m8[0], 32));

  float mref = mrun;
  if (!__all(mx <= mrun + 8.0f)) {
    const float mnew = fmaxf(mrun, mx);
    const float corr = __builtin_amdgcn_exp2f(mrun - mnew);
    mrun = mnew; mref = mnew;
    srun *= corr;
#pragma unroll
    for (int r = 0; r < 16; ++r) { oacc[0][r] *= corr; oacc[1][r] *= corr; }
  }

  float psum = 0.0f;
#pragma unroll
  for (int r = 0; r < 16; ++r) {
    s0[r] = __builtin_amdgcn_exp2f(s0[r] - mref);
    s1[r] = __builtin_amdgcn_exp2f(s1[r] - mref);
    psum += s0[r] + s1[r];
  }
  srun += psum;

  upw pw[4];
#pragma unroll
  for (int cl = 0; cl < 2; ++cl) {
    {
      u32 a01 = pkbf(s0[8 * cl + 0], s0[8 * cl + 1]);
      u32 a23 = pkbf(s0[8 * cl + 2], s0[8 * cl + 3]);
      u32 b01 = pkbf(s0[8 * cl + 4], s0[8 * cl + 5]);
      u32 b23 = pkbf(s0[8 * cl + 6], s0[8 * cl + 7]);
      asm("v_permlane32_swap_b32 %0, %1" : "+v"(a01), "+v"(b01));
      asm("v_permlane32_swap_b32 %0, %1" : "+v"(a23), "+v"(b23));
      pw[cl].w[0] = a01; pw[cl].w[1] = a23; pw[cl].w[2] = b01; pw[cl].w[3] = b23;
    }
    {
      u32 a01 = pkbf(s1[8 * cl + 0], s1[8 * cl + 1]);
      u32 a23 = pkbf(s1[8 * cl + 2], s1[8 * cl + 3]);
      u32 b01 = pkbf(s1[8 * cl + 4], s1[8 * cl + 5]);
      u32 b23 = pkbf(s1[8 * cl + 6], s1[8 * cl + 7]);
      asm("v_permlane32_swap_b32 %0, %1" : "+v"(a01), "+v"(b01));
      asm("v_permlane32_swap_b32 %0, %1" : "+v"(a23), "+v"(b23));
      pw[2 + cl].w[0] = a01; pw[2 + cl].w[1] = a23; pw[2 + cl].w[2] = b01; pw[2 + cl].w[3] = b23;
    }
  }

  __builtin_amdgcn_s_setprio(1);
#pragma unroll
  for (int dh = 0; dh < 2; ++dh) {
    const char* vrow = vbase + (32 * dh + l31) * 128;
#pragma unroll
    for (int c = 0; c < 4; ++c) {
      bf16x8 vf = *reinterpret_cast<const bf16x8*>(vrow + (((2 * c + hi) * 16) ^ swz));
      oacc[dh] = __builtin_amdgcn_mfma_f32_32x32x16_bf16(vf, pw[c].v, oacc[dh], 0, 0, 0);
    }
  }
  __builtin_amdgcn_s_setprio(0);
}

// ---------------- causal flash attention: 8-wave band-split blocks -----------------
// block = (bh, pair p), 512 threads: waves 0-3 = band H (qt=15-p), waves 4-7 =
// band L (qt=p), each wave 32 q rows. One shared KV stream; 4 waves/SIMD.
__global__ __launch_bounds__(512, 4) void attn_kernel(const bf16* __restrict__ Qh,
                                                      const bf16* __restrict__ Kh,
                                                      const bf16* __restrict__ VhT,
                                                      bf16* __restrict__ aout) {
  __shared__ __align__(16) bf16 lK[2][64 * 64];
  __shared__ __align__(16) bf16 lVT[2][64 * 64];
  const int tid  = threadIdx.x;
  const int lane = tid & 63, wave = tid >> 6;   // 0..7
  const int l31  = lane & 31;
  const int hi   = lane >> 5;
  const int bid  = blockIdx.x;              // 0..511; same-bh blocks share an XCD
  const int bh   = bid & 63;
  const int p    = bid >> 6;                // 0..7
  const int qtH  = 15 - p, qtL = p;
  const int band = wave >> 2;               // 0 = H, 1 = L
  const int qt   = band ? qtL : qtH;
  const int q0w  = qt * 128 + (wave & 3) * 32;
  const int b    = bh >> 4, h = bh & 15;
  const size_t tb = (size_t)b * TT;
  const int swz  = (l31 & 7) << 4;

  // Q fragments (one band per wave), pre-scaled by 0.125*log2(e)
  const float QSCALE = 0.18033688011112042f;
  bf16x8 qfr[4];
  {
    const bf16* qrow = Qh + ((size_t)bh * TT + q0w + l31) * HDIM;
#pragma unroll
    for (int dc = 0; dc < 4; ++dc) {
      bf16x8 v = *reinterpret_cast<const bf16x8*>(qrow + dc * 16 + hi * 8);
      bf16x8 o;
#pragma unroll
      for (int j = 0; j < 8; ++j) o[j] = (bf16)((float)v[j] * QSCALE);
      qfr[dc] = o;
    }
  }

  f32x16 oacc[2] = {};
  float mrun = -3e38f, srun = 0.0f;

  // staging: 512 threads cover one 64x64 K tile + one 64x64 V^T tile (1+1 loads)
  const int r0 = tid >> 3;                  // 0..63
  const int sg = tid & 7;
  const int seg = sg ^ (r0 & 7);
  const bf16* kS = Kh + ((size_t)bh * TT + r0) * HDIM + (size_t)seg * 8;
  const bf16* vS = VhT + ((size_t)bh * HDIM + r0) * TT + (size_t)seg * 8;

  const int nkv = 2 * qtH + 2;              // loop bound for ALL waves

  gload_lds16(kS, &lK[0][tid * 8]);
  gload_lds16(vS, &lVT[0][tid * 8]);
  __syncthreads();

  int cur = 0;
  for (int t = 0; t < nkv; ++t) {
    const int kv0 = t * 64;
    if (t + 1 < nkv) {
      const int kvn = kv0 + 64;
      gload_lds16(kS + (size_t)kvn * HDIM, &lK[cur ^ 1][tid * 8]);
      gload_lds16(vS + kvn, &lVT[cur ^ 1][tid * 8]);
    }

    if (kv0 <= q0w + 31)
      attn_tile((const char*)&lK[cur][0], (const char*)&lVT[cur][0],
                qfr, oacc, mrun, srun, kv0, q0w, l31, hi, swz);

    __syncthreads();   // drains prefetch + protects dbuf swap
    cur ^= 1;
  }

  // ---- epilogue: cross-lane rowsum, divide, store (one band per wave)
  {
    srun += __shfl_xor(srun, 32);
    const float inv = 1.0f / srun;
    const int q = q0w + l31;
    bf16* orow = aout + (tb + q) * (size_t)EMBED + h * HDIM;
#pragma unroll
    for (int dh = 0; dh < 2; ++dh)
#pragma unroll
      for (int rb = 0; rb < 4; ++rb) {
        bf16x4 o4;
#pragma unroll
        for (int k = 0; k < 4; ++k) o4[k] = (bf16)(oacc[dh][4 * rb + k] * inv);
        *reinterpret_cast<bf16x4*>(orow + 32 * dh + 8 * rb + 4 * hi) = o4;
      }
  }
}

extern "C" void kernel_launch(void* const* d_in, const int* in_sizes, int n_in,
                              void* d_out, int out_size, void* d_ws, size_t ws_size,
                              hipStream_t stream) {
  const float* x      = (const float*)d_in[0];
  const float* qkv_w  = (const float*)d_in[1];
  const float* qkv_b  = (const float*)d_in[2];
  const float* proj_w = (const float*)d_in[3];
  const float* proj_b = (const float*)d_in[4];
  float* out = (float*)d_out;

  const size_t QSZ = (size_t)BB * NHEAD * TT * HDIM;
  char* ws = (char*)d_ws;
  bf16* xb    = (bf16*)ws;
  bf16* wqkv  = xb + (size_t)MTOK * EMBED;
  bf16* wproj = wqkv + (size_t)C3 * EMBED;
  bf16* Qh    = wproj + (size_t)EMBED * EMBED;
  bf16* Kh    = Qh + QSZ;
  bf16* VhT   = Kh + QSZ;
  bf16* aob   = xb;   // alias: xb dead after gemm_qkv

  const int NCVT = (MTOK * EMBED + C3 * EMBED + EMBED * EMBED) / 4;
  cvt_all<<<dim3((NCVT + 255) / 256), dim3(256), 0, stream>>>(x, qkv_w, proj_w,
                                                              xb, wqkv, wproj);

  gemm_qkv<<<dim3(C3 / 128, MTOK / 128), dim3(256), 0, stream>>>(xb, wqkv, qkv_b, Qh, Kh, VhT);

  attn_kernel<<<dim3(512), dim3(512), 0, stream>>>(Qh, Kh, VhT, aob);

  gemm_bt<<<dim3(EMBED / 128, MTOK / 128), dim3(256), 0, stream>>>(
      aob, wproj, proj_b, out, MTOK, EMBED, EMBED);
}

// Round 16
// 160.293 us; speedup vs baseline: 1.2648x; 1.0147x over previous
//
#include <hip/hip_runtime.h>

#define EMBED 1024
#define C3    3072
#define NHEAD 16
#define HDIM  64
#define BB    4
#define TT    2048
#define MTOK  8192   // BB*TT

typedef __bf16 bf16;
typedef __bf16 bf16x4 __attribute__((ext_vector_type(4)));
typedef __bf16 bf16x8 __attribute__((ext_vector_type(8)));
typedef float  f32x4  __attribute__((ext_vector_type(4)));
typedef float  f32x16 __attribute__((ext_vector_type(16)));
typedef unsigned int u32;

__device__ __forceinline__ void gload_lds16(const bf16* g, bf16* l) {
  __builtin_amdgcn_global_load_lds((__attribute__((address_space(1))) void*)g,
                                   (__attribute__((address_space(3))) void*)l,
                                   16, 0, 0);
}

__device__ __forceinline__ u32 pkbf(float lo, float hi_) {
  union { bf16 h[2]; u32 w; } u;
  u.h[0] = (bf16)lo; u.h[1] = (bf16)hi_;
  return u.w;
}

union upw { u32 w[4]; bf16x8 v; };

// ---------------- fused fp32 -> bf16 convert ----------------
__global__ __launch_bounds__(256) void cvt_all(const float* __restrict__ x,
                                               const float* __restrict__ w1,
                                               const float* __restrict__ w2,
                                               bf16* __restrict__ xb,
                                               bf16* __restrict__ wqkv,
                                               bf16* __restrict__ wproj) {
  const int N1 = MTOK * EMBED, N2 = C3 * EMBED, N3 = EMBED * EMBED;
  int i = (blockIdx.x * blockDim.x + threadIdx.x) * 4;
  const float* src; bf16* dst;
  if (i < N1)           { src = x + i;            dst = xb + i; }
  else if (i < N1 + N2) { src = w1 + (i - N1);    dst = wqkv + (i - N1); }
  else if (i < N1 + N2 + N3) { src = w2 + (i - N1 - N2); dst = wproj + (i - N1 - N2); }
  else return;
  float4 v = *reinterpret_cast<const float4*>(src);
  bf16x4 o;
  o[0] = (bf16)v.x; o[1] = (bf16)v.y; o[2] = (bf16)v.z; o[3] = (bf16)v.w;
  *reinterpret_cast<bf16x4*>(dst) = o;
}

// ================= GEMM core (R10: BK=64, swizzled LDS, hoisted addressing) ========
__device__ __forceinline__ void gemm_core(const bf16* __restrict__ A,
                                          const bf16* __restrict__ W,
                                          int K, int bm0, int bn0,
                                          int wm, int wn, int l15, int lg,
                                          f32x4 (&acc)[4][4]) {
  __shared__ __align__(16) bf16 lA[128 * 64];
  __shared__ __align__(16) bf16 lB[128 * 64];
  const int tid  = threadIdx.x;
  const int grow = tid >> 3;
  const int gseg = tid & 7;

  const bf16* srcA[4];
  const bf16* srcB[4];
#pragma unroll
  for (int r = 0; r < 4; ++r) {
    const int row = r * 32 + grow;
    const int seg = gseg ^ (row & 7);
    srcA[r] = A + (size_t)(bm0 + row) * K + seg * 8;
    srcB[r] = W + (size_t)(bn0 + row) * K + seg * 8;
  }
  int offA[2][4], offB[2][4];
#pragma unroll
  for (int kk = 0; kk < 2; ++kk) {
#pragma unroll
    for (int i = 0; i < 4; ++i) {
      const int rowA = wm + i * 16 + l15;
      const int rowB = wn + i * 16 + l15;
      offA[kk][i] = rowA * 128 + ((kk * 64 + lg * 16) ^ ((rowA & 7) << 4));
      offB[kk][i] = rowB * 128 + ((kk * 64 + lg * 16) ^ ((rowB & 7) << 4));
    }
  }

  for (int kt = 0; kt < K; kt += 64) {
#pragma unroll
    for (int r = 0; r < 4; ++r) {
      gload_lds16(srcA[r] + kt, &lA[(r * 256 + tid) * 8]);
      gload_lds16(srcB[r] + kt, &lB[(r * 256 + tid) * 8]);
    }
    __syncthreads();
    const char* Ab = (const char*)lA;
    const char* Bb = (const char*)lB;
#pragma unroll
    for (int kk = 0; kk < 2; ++kk) {
      bf16x8 af[4], bf_[4];
#pragma unroll
      for (int i = 0; i < 4; ++i) af[i]  = *reinterpret_cast<const bf16x8*>(Ab + offA[kk][i]);
#pragma unroll
      for (int j = 0; j < 4; ++j) bf_[j] = *reinterpret_cast<const bf16x8*>(Bb + offB[kk][j]);
#pragma unroll
      for (int i = 0; i < 4; ++i)
#pragma unroll
        for (int j = 0; j < 4; ++j)
          acc[i][j] = __builtin_amdgcn_mfma_f32_16x16x32_bf16(af[i], bf_[j],
                                                              acc[i][j], 0, 0, 0);
    }
    __syncthreads();
  }
}

// ---------------- GEMM1: qkv = x @ qkv_w^T + b, per-head layouts, XCD-tiled --------
__global__ __launch_bounds__(256) void gemm_qkv(const bf16* __restrict__ A,
                                                const bf16* __restrict__ W,
                                                const float* __restrict__ bias,
                                                bf16* __restrict__ Qh,
                                                bf16* __restrict__ Kh,
                                                bf16* __restrict__ VhT) {
  const int tid  = threadIdx.x;
  const int lane = tid & 63, wave = tid >> 6;
  const int wm   = (wave >> 1) * 64;
  const int wn   = (wave & 1) * 64;
  // XCD-tiled remap (bijective, 1536 % 8 == 0): XCD g owns M-rows [8g, 8g+8),
  // x-major inner order -> per-XCD L2 working set ~ 8 A-panels + streaming B.
  const int bidx = blockIdx.x;
  const int g  = bidx & 7;
  const int i_ = bidx >> 3;                 // 0..191
  const int bm0 = (g * 8 + (i_ & 7)) * 128;
  const int bn0 = (i_ >> 3) * 128;          // 0..23
  const int l15  = lane & 15, lg = lane >> 4;

  f32x4 acc[4][4] = {};
  gemm_core(A, W, EMBED, bm0, bn0, wm, wn, l15, lg, acc);

  const int sec = bn0 >> 10;   // 0=Q 1=K 2=V, uniform per block
#pragma unroll
  for (int i = 0; i < 4; ++i)
#pragma unroll
    for (int j = 0; j < 4; ++j) {
      const int col = bn0 + wn + j * 16 + l15;
      const float bs = bias[col];
      const int c2 = col & 1023, hh = c2 >> 6, dd = c2 & 63;
      const int rowb = bm0 + wm + i * 16 + lg * 4;
      const int bb = rowb >> 11, t0 = rowb & 2047;
      const int bh = bb * 16 + hh;
      if (sec < 2) {
        bf16* dst = (sec ? Kh : Qh) + ((size_t)bh * TT + t0) * HDIM + dd;
#pragma unroll
        for (int r = 0; r < 4; ++r) dst[(size_t)r * HDIM] = (bf16)(acc[i][j][r] + bs);
      } else {
        bf16x4 o4;
#pragma unroll
        for (int r = 0; r < 4; ++r) o4[r] = (bf16)(acc[i][j][r] + bs);
        *reinterpret_cast<bf16x4*>(VhT + ((size_t)bh * HDIM + dd) * TT + t0) = o4;
      }
    }
}

// ---------------- GEMM2: out = A @ W^T + b (fp32 out) ----------------
__global__ __launch_bounds__(256) void gemm_bt(const bf16* __restrict__ A,
                                               const bf16* __restrict__ W,
                                               const float* __restrict__ bias,
                                               float* __restrict__ Cf,
                                               int M, int N, int K) {
  const int tid  = threadIdx.x;
  const int lane = tid & 63, wave = tid >> 6;
  const int wm   = (wave >> 1) * 64;
  const int wn   = (wave & 1) * 64;
  const int bn0  = blockIdx.x * 128;
  const int bm0  = blockIdx.y * 128;
  const int l15  = lane & 15, lg = lane >> 4;

  f32x4 acc[4][4] = {};
  gemm_core(A, W, K, bm0, bn0, wm, wn, l15, lg, acc);

#pragma unroll
  for (int i = 0; i < 4; ++i)
#pragma unroll
    for (int j = 0; j < 4; ++j) {
      int col = bn0 + wn + j * 16 + l15;
      float bs = bias[col];
#pragma unroll
      for (int r = 0; r < 4; ++r) {
        int row = bm0 + wm + i * 16 + lg * 4 + r;
        Cf[(size_t)row * N + col] = acc[i][j][r] + bs;
      }
    }
}

// ---------------- one 32q x 64kv attention tile (R10-verified math) ----------------
// kbase: K sub-tile base ([64 kv][64 d], 128B rows). vbase: V^T kv-half base
// within 256B rows (stride 256B).
__device__ __forceinline__ void attn_tile(const char* kbase, const char* vbase,
                                          const bf16x8 (&qfr)[4], f32x16 (&oacc)[2],
                                          float& mrun, float& srun,
                                          const int kv0, const int q0w,
                                          const int l31, const int hi, const int swz) {
  f32x16 s0 = {}, s1 = {};
  __builtin_amdgcn_s_setprio(1);
#pragma unroll
  for (int dc = 0; dc < 4; ++dc) {
    bf16x8 kf = *reinterpret_cast<const bf16x8*>(
        kbase + l31 * 128 + (((2 * dc + hi) * 16) ^ swz));
    s0 = __builtin_amdgcn_mfma_f32_32x32x16_bf16(kf, qfr[dc], s0, 0, 0, 0);
  }
#pragma unroll
  for (int dc = 0; dc < 4; ++dc) {
    bf16x8 kf = *reinterpret_cast<const bf16x8*>(
        kbase + (32 + l31) * 128 + (((2 * dc + hi) * 16) ^ swz));
    s1 = __builtin_amdgcn_mfma_f32_32x32x16_bf16(kf, qfr[dc], s1, 0, 0, 0);
  }
  __builtin_amdgcn_s_setprio(0);

  if (kv0 + 63 > q0w) {
    const int qg = q0w + l31;
#pragma unroll
    for (int r = 0; r < 16; ++r) {
      const int kvb = kv0 + (r & 3) + 8 * (r >> 2) + 4 * hi;
      if (kvb > qg)      s0[r] = -3e38f;
      if (kvb + 32 > qg) s1[r] = -3e38f;
    }
  }

  float m8[8];
#pragma unroll
  for (int i = 0; i < 8; ++i)
    m8[i] = fmaxf(fmaxf(s0[i], s0[i + 8]), fmaxf(s1[i], s1[i + 8]));
#pragma unroll
  for (int st = 4; st > 0; st >>= 1)
#pragma unroll
    for (int i = 0; i < st; ++i) m8[i] = fmaxf(m8[i], m8[i + st]);
  float mx = fmaxf(m8[0], __shfl_xor(m8[0], 32));

  float mref = mrun;
  if (!__all(mx <= mrun + 8.0f)) {
    const float mnew = fmaxf(mrun, mx);
    const float corr = __builtin_amdgcn_exp2f(mrun - mnew);
    mrun = mnew; mref = mnew;
    srun *= corr;
#pragma unroll
    for (int r = 0; r < 16; ++r) { oacc[0][r] *= corr; oacc[1][r] *= corr; }
  }

  float psum = 0.0f;
#pragma unroll
  for (int r = 0; r < 16; ++r) {
    s0[r] = __builtin_amdgcn_exp2f(s0[r] - mref);
    s1[r] = __builtin_amdgcn_exp2f(s1[r] - mref);
    psum += s0[r] + s1[r];
  }
  srun += psum;

  upw pw[4];
#pragma unroll
  for (int cl = 0; cl < 2; ++cl) {
    {
      u32 a01 = pkbf(s0[8 * cl + 0], s0[8 * cl + 1]);
      u32 a23 = pkbf(s0[8 * cl + 2], s0[8 * cl + 3]);
      u32 b01 = pkbf(s0[8 * cl + 4], s0[8 * cl + 5]);
      u32 b23 = pkbf(s0[8 * cl + 6], s0[8 * cl + 7]);
      asm("v_permlane32_swap_b32 %0, %1" : "+v"(a01), "+v"(b01));
      asm("v_permlane32_swap_b32 %0, %1" : "+v"(a23), "+v"(b23));
      pw[cl].w[0] = a01; pw[cl].w[1] = a23; pw[cl].w[2] = b01; pw[cl].w[3] = b23;
    }
    {
      u32 a01 = pkbf(s1[8 * cl + 0], s1[8 * cl + 1]);
      u32 a23 = pkbf(s1[8 * cl + 2], s1[8 * cl + 3]);
      u32 b01 = pkbf(s1[8 * cl + 4], s1[8 * cl + 5]);
      u32 b23 = pkbf(s1[8 * cl + 6], s1[8 * cl + 7]);
      asm("v_permlane32_swap_b32 %0, %1" : "+v"(a01), "+v"(b01));
      asm("v_permlane32_swap_b32 %0, %1" : "+v"(a23), "+v"(b23));
      pw[2 + cl].w[0] = a01; pw[2 + cl].w[1] = a23; pw[2 + cl].w[2] = b01; pw[2 + cl].w[3] = b23;
    }
  }

  __builtin_amdgcn_s_setprio(1);
#pragma unroll
  for (int dh = 0; dh < 2; ++dh) {
    const char* vrow = vbase + (32 * dh + l31) * 256;
#pragma unroll
    for (int c = 0; c < 4; ++c) {
      bf16x8 vf = *reinterpret_cast<const bf16x8*>(vrow + (((2 * c + hi) * 16) ^ swz));
      oacc[dh] = __builtin_amdgcn_mfma_f32_32x32x16_bf16(vf, pw[c].v, oacc[dh], 0, 0, 0);
    }
  }
  __builtin_amdgcn_s_setprio(0);
}

// ---------------- causal flash attention: 8-wave band-split, KVBLK=128 -------------
// block = (bh, pair p), 512 threads: waves 0-3 = band H (qt=15-p), waves 4-7 =
// band L (qt=p). KV staged in 128-kv tiles (half the barriers of KVBLK=64).
// ALL gload_lds LDS destinations are lane-linear (rule #21); permutations are
// applied on the global SOURCE address only.
__global__ __launch_bounds__(512, 4) void attn_kernel(const bf16* __restrict__ Qh,
                                                      const bf16* __restrict__ Kh,
                                                      const bf16* __restrict__ VhT,
                                                      bf16* __restrict__ aout) {
  __shared__ __align__(16) bf16 lK[2][128 * 64];    // [kv 128][d 64], 8 slots/row
  __shared__ __align__(16) bf16 lVT[2][64 * 128];   // [d 64][kv 128], 2x8 slots/row
  const int tid  = threadIdx.x;
  const int lane = tid & 63, wave = tid >> 6;   // 0..7
  const int l31  = lane & 31;
  const int hi   = lane >> 5;
  const int bid  = blockIdx.x;              // 0..511; same-bh blocks share an XCD
  const int bh   = bid & 63;
  const int p    = bid >> 6;                // 0..7
  const int qtH  = 15 - p, qtL = p;
  const int band = wave >> 2;               // 0 = H, 1 = L
  const int qt   = band ? qtL : qtH;
  const int q0w  = qt * 128 + (wave & 3) * 32;
  const int b    = bh >> 4, h = bh & 15;
  const size_t tb = (size_t)b * TT;
  const int swz  = (l31 & 7) << 4;

  // Q fragments (one band per wave), pre-scaled by 0.125*log2(e)
  const float QSCALE = 0.18033688011112042f;
  bf16x8 qfr[4];
  {
    const bf16* qrow = Qh + ((size_t)bh * TT + q0w + l31) * HDIM;
#pragma unroll
    for (int dc = 0; dc < 4; ++dc) {
      bf16x8 v = *reinterpret_cast<const bf16x8*>(qrow + dc * 16 + hi * 8);
      bf16x8 o;
#pragma unroll
      for (int j = 0; j < 8; ++j) o[j] = (bf16)((float)v[j] * QSCALE);
      qfr[dc] = o;
    }
  }

  f32x16 oacc[2] = {};
  float mrun = -3e38f, srun = 0.0f;

  // ---- K staging: dest &lK[r0*64 + sg*8] is lane-linear (wave base + lane*16B).
  const int r0 = tid >> 3;                  // 0..63
  const int sg = tid & 7;
  const int segK = sg ^ (r0 & 7);
  const bf16* kS = Kh + ((size_t)bh * TT + r0) * HDIM + (size_t)segK * 8;
  bf16* kD0 = &lK[0][r0 * 64 + sg * 8];               // rows 0..63
  bf16* kD1 = &lK[0][(r0 + 64) * 64 + sg * 8];        // rows 64..127
  // ---- V staging: dest tid*8 / (tid+512)*8 is literally linear; source swizzled.
  // dest elem tid*8 = (row rv = tid>>4, half hs = (tid>>3)&1, slot j = tid&7);
  // slot j of half hs must hold chunk j^(rv&7) of that half.
  const int rv = tid >> 4;                  // 0..31
  const int hs = (tid >> 3) & 1;
  const int jv = tid & 7;
  const int cv = jv ^ (rv & 7);             // (rv+32)&7 == rv&7, reuse for load 1
  const bf16* vS0 = VhT + ((size_t)bh * HDIM + rv) * TT + hs * 64 + (size_t)cv * 8;
  const bf16* vS1 = VhT + ((size_t)bh * HDIM + rv + 32) * TT + hs * 64 + (size_t)cv * 8;
  bf16* vD0 = &lVT[0][tid * 8];                        // rows 0..31
  bf16* vD1 = &lVT[0][(tid + 512) * 8];                // rows 32..63
  const int lKsz = 128 * 64, lVsz = 64 * 128;

  const int nkvt = qtH + 1;                 // 128-kv tiles (uniform loop bound)

  // prologue: stage tile 0 into buf 0
  gload_lds16(kS,             kD0);
  gload_lds16(kS + 64 * HDIM, kD1);
  gload_lds16(vS0,            vD0);
  gload_lds16(vS1,            vD1);
  __syncthreads();

  int cur = 0;
  for (int t = 0; t < nkvt; ++t) {
    if (t + 1 < nkvt) {
      const size_t kv = (size_t)(t + 1) * 128;
      const int bo = (cur ^ 1);
      gload_lds16(kS + kv * HDIM,        kD0 + bo * lKsz);
      gload_lds16(kS + (kv + 64) * HDIM, kD1 + bo * lKsz);
      gload_lds16(vS0 + kv,              vD0 + bo * lVsz);
      gload_lds16(vS1 + kv,              vD1 + bo * lVsz);
    }

#pragma unroll
    for (int s = 0; s < 2; ++s) {
      const int kv0 = t * 128 + s * 64;
      if (kv0 <= q0w + 31)
        attn_tile((const char*)&lK[cur][0] + s * 8192,
                  (const char*)&lVT[cur][0] + s * 128,
                  qfr, oacc, mrun, srun, kv0, q0w, l31, hi, swz);
    }

    __syncthreads();   // drains prefetch + protects dbuf swap
    cur ^= 1;
  }

  // ---- epilogue: cross-lane rowsum, divide, store (one band per wave)
  {
    srun += __shfl_xor(srun, 32);
    const float inv = 1.0f / srun;
    const int q = q0w + l31;
    bf16* orow = aout + (tb + q) * (size_t)EMBED + h * HDIM;
#pragma unroll
    for (int dh = 0; dh < 2; ++dh)
#pragma unroll
      for (int rb = 0; rb < 4; ++rb) {
        bf16x4 o4;
#pragma unroll
        for (int k = 0; k < 4; ++k) o4[k] = (bf16)(oacc[dh][4 * rb + k] * inv);
        *reinterpret_cast<bf16x4*>(orow + 32 * dh + 8 * rb + 4 * hi) = o4;
      }
  }
}

extern "C" void kernel_launch(void* const* d_in, const int* in_sizes, int n_in,
                              void* d_out, int out_size, void* d_ws, size_t ws_size,
                              hipStream_t stream) {
  const float* x      = (const float*)d_in[0];
  const float* qkv_w  = (const float*)d_in[1];
  const float* qkv_b  = (const float*)d_in[2];
  const float* proj_w = (const float*)d_in[3];
  const float* proj_b = (const float*)d_in[4];
  float* out = (float*)d_out;

  const size_t QSZ = (size_t)BB * NHEAD * TT * HDIM;
  char* ws = (char*)d_ws;
  bf16* xb    = (bf16*)ws;
  bf16* wqkv  = xb + (size_t)MTOK * EMBED;
  bf16* wproj = wqkv + (size_t)C3 * EMBED;
  bf16* Qh    = wproj + (size_t)EMBED * EMBED;
  bf16* Kh    = Qh + QSZ;
  bf16* VhT   = Kh + QSZ;
  bf16* aob   = xb;   // alias: xb dead after gemm_qkv

  const int NCVT = (MTOK * EMBED + C3 * EMBED + EMBED * EMBED) / 4;
  cvt_all<<<dim3((NCVT + 255) / 256), dim3(256), 0, stream>>>(x, qkv_w, proj_w,
                                                              xb, wqkv, wproj);

  gemm_qkv<<<dim3(1536), dim3(256), 0, stream>>>(xb, wqkv, qkv_b, Qh, Kh, VhT);

  attn_kernel<<<dim3(512), dim3(512), 0, stream>>>(Qh, Kh, VhT, aob);

  gemm_bt<<<dim3(EMBED / 128, MTOK / 128), dim3(256), 0, stream>>>(
      aob, wproj, proj_b, out, MTOK, EMBED, EMBED);
}